// Round 18
// baseline (355.490 us; speedup 1.0000x reference)
//
#include <hip/hip_runtime.h>
#include <math.h>

#define LLEN 8192
#define DDIM 1024
#define NB   2
#define NMODE 512
#define MFFT 8192
#define SLEN 4096        // truncated kernel length (K[l]=0 beyond; worst-case e^-20)
#define KF_STRIDE 8208   // float2 per Kf row (8193 used)

// XOR-swizzled LDS index (bijective), buffer exactly 64 KB.
#define PIDX(i) ((i) ^ (((i) >> 4) & 15))
#define FBUF 8192        // float2 per buffer = 65,536 B exactly

// ---------------- workspace layout (bytes), total ~172.4 MB ----------------
#define OFF_UT   ((size_t)0)            // u_T [B,D,L] f32 (y+res in place)  67,108,864
#define OFF_KF   ((size_t)67108864)     // Kf [D,KF_STRIDE] float2           67,239,936
#define OFF_KT   ((size_t)134348800)    // K_T [D][SLEN] f32                 16,777,216
#define OFF_CPK  ((size_t)167903232)    // Cpk [512][1024] float2             4,194,304
#define OFF_MEAN ((size_t)172097536)    // mean [B,L] f32                        65,536
#define OFF_RSTD ((size_t)172163072)    // rstd [B,L] f32                        65,536
#define OFF_LAMR ((size_t)172228608)    // f32[512]
#define OFF_LAMID ((size_t)172230656)   // f64[512] (4096 B)
#define OFF_WR   ((size_t)172234752)    // f32[512]
#define OFF_WI   ((size_t)172236800)    // f32[512]
#define OFF_CUT  ((size_t)172238848)    // int[512]
#define OFF_TW   ((size_t)172240896)    // twH: 8192 float2 (hierarchical)      65,536
#define OFF_TWR  ((size_t)172306432)    // 8193 float2 (2pi k/16384)            65,544
#define OFF_SORTN ((size_t)172371976)   // int[512] rank->mode                    2,048
#define OFF_TCNT  ((size_t)172374024)   // int[16] per-l-tile active prefix          64
#define WS_NEED  ((size_t)172374088)

// Spack overlay inside the KF region (dead until kf_fft writes KF)
#define OFF_SP   OFF_KF

// ---------------- LayerNorm stats: mean/rstd per (b,l) row ----------------
__global__ __launch_bounds__(256) void ln_stats_kernel(const float* __restrict__ x,
                                                       float* __restrict__ mean,
                                                       float* __restrict__ rstd) {
  __shared__ float red[16];
  int row = blockIdx.x;            // b*L + l
  int tid = threadIdx.x;
  const float4* xr = (const float4*)(x + (size_t)row * DDIM);
  float4 v = xr[tid];
  float s = v.x + v.y + v.z + v.w;
  float q = v.x*v.x + v.y*v.y + v.z*v.z + v.w*v.w;
  #pragma unroll
  for (int off = 32; off; off >>= 1) { s += __shfl_down(s, off); q += __shfl_down(q, off); }
  int wid = tid >> 6;
  if ((tid & 63) == 0) { red[wid] = s; red[8 + wid] = q; }
  __syncthreads();
  if (tid == 0) {
    float ts = red[0] + red[1] + red[2] + red[3];
    float tq = red[8] + red[9] + red[10] + red[11];
    float m = ts * (1.0f / DDIM);
    float var = tq * (1.0f / DDIM) - m * m;
    mean[row] = m;
    rstd[row] = rsqrtf(var + 1e-5f);
  }
}

// ---------------- fused LN + transpose: x[B,L,D] -> uT[B,D,L] ----------------
__global__ __launch_bounds__(256) void transpose_ln_kernel(const float* __restrict__ x,
                                                           const float* __restrict__ mean,
                                                           const float* __restrict__ rstd,
                                                           const float* __restrict__ gamma,
                                                           const float* __restrict__ beta,
                                                           float* __restrict__ uT) {
  __shared__ float tile[32][33];
  int lt = blockIdx.x * 32, dt = blockIdx.y * 32, b = blockIdx.z;
  int c = threadIdx.x & 31, r0 = threadIdx.x >> 5;
  float gv = gamma[dt + c], bv = beta[dt + c];
  #pragma unroll
  for (int i = 0; i < 4; i++) {
    int r = r0 + i * 8;   // l within tile
    float m = mean[(size_t)b * LLEN + lt + r];
    float rs = rstd[(size_t)b * LLEN + lt + r];
    float xv = x[((size_t)b * LLEN + lt + r) * DDIM + dt + c];
    tile[r][c] = (xv - m) * rs * gv + bv;
  }
  __syncthreads();
  #pragma unroll
  for (int i = 0; i < 4; i++) {
    int r = r0 + i * 8;   // d within tile
    uT[((size_t)b * DDIM + dt + r) * LLEN + lt + c] = tile[c][r];
  }
}

// ---------------- params + twiddle tables (all one-time, double precision) ----------------
__global__ void build_tables_kernel(const float* __restrict__ Lr, const float* __restrict__ Li,
                                    float* lamr, double* lamid, float* wre, float* wim, int* cut,
                                    float2* twH, float2* twR) {
  int gid = blockIdx.x * 256 + threadIdx.x;
  if (gid < NMODE) {
    double lr = (double)Lr[gid], li = (double)Li[gid];
    double ar = -exp(lr);      // Re(Lam)  (negative)
    double ai = exp(li);       // Im(Lam)
    lamr[gid] = (float)ar;
    lamid[gid] = ai;
    double em = exp(ar);
    double cs = cos(ai), sn = sin(ai);
    double er = em * cs - 1.0;     // exp(Lam) - 1
    double ei = em * sn;
    double den = ar * ar + ai * ai;
    wre[gid] = (float)((er * ar + ei * ai) / den);   // (exp(Lam)-1)/Lam
    wim[gid] = (float)((ei * ar - er * ai) / den);
    int co = (int)(40.0 / (-ar)) + 1;                // exp(ar*l) < e^-40 beyond
    cut[gid] = co > SLEN ? SLEN : co;                // clamp to truncated domain
  }
  int j = gid - NMODE;
  if (j >= 0 && j < 8192) {
    // hierarchical twiddle: twH[Ls + p] = (cos(pi*p/Ls), +sin(pi*p/Ls)).
    // Applied as (w.x, sign*w.y): sign=-1 (fwd) -> e^{-i a}, sign=+1 (inv) -> e^{+i a}.
    if (j == 0) {
      twH[0] = make_float2(1.f, 0.f);
    } else {
      int lev = 31 - __clz(j);
      int Ls = 1 << lev;
      int p = j - Ls;
      double a = 3.14159265358979323846264338 * (double)p / (double)Ls;
      twH[j] = make_float2((float)cos(a), (float)sin(a));
    }
  }
  int k = gid - (NMODE + 8192);
  if (k >= 0 && k <= 8192) {
    double a = 6.283185307179586476925287 * (double)k / 16384.0;
    twR[k] = make_float2((float)cos(a), (float)sin(a));
  }
}

// ---------------- sort modes by cut descending (rank), per-tile prefix counts ----------------
#define KB4_LT 256
#define NTILE (SLEN / KB4_LT)   // 16
__global__ __launch_bounds__(NMODE) void sortmodes_kernel(const int* __restrict__ cut,
                                                          int* __restrict__ sortn,
                                                          int* __restrict__ tcount) {
  __shared__ int sc[NMODE];
  int tid = threadIdx.x;
  sc[tid] = cut[tid];
  __syncthreads();
  int c = sc[tid];
  int rank = 0;
  for (int m = 0; m < NMODE; ++m) {
    int cm = sc[m];
    rank += (cm > c) || (cm == c && m < tid);
  }
  sortn[rank] = tid;
  if (tid < NTILE) {
    int l0 = tid * KB4_LT;
    int cnt = 0;
    for (int m = 0; m < NMODE; ++m) cnt += (sc[m] > l0);
    tcount[tid] = cnt;
  }
}

// ---------------- Cpk[r][d] = (Cr[d][n]+i Ci[d][n]) * W[n], n = sortn[r] ----------------
__global__ __launch_bounds__(256) void cpack_kernel(const float* __restrict__ Cr,
                                                    const float* __restrict__ Ci,
                                                    const float* __restrict__ wre,
                                                    const float* __restrict__ wim,
                                                    const int* __restrict__ sortn,
                                                    float2* __restrict__ Cpk) {
  int idx = blockIdx.x * 256 + threadIdx.x;   // r*D + d  (d fastest -> coalesced writes)
  int r = idx >> 10, d = idx & (DDIM - 1);
  int n = sortn[r];
  float cr = Cr[(size_t)d * NMODE + n], ci = Ci[(size_t)d * NMODE + n];
  float wr = wre[n], wi = wim[n];
  Cpk[idx] = make_float2(cr * wr - ci * wi, cr * wi + ci * wr);
}

// ---------------- Spack[r][l] = exp(Lam_{sortn[r]} l), zero beyond cut ----------------
__global__ __launch_bounds__(256) void sbuild_kernel(const float* __restrict__ lamr,
                                                     const double* __restrict__ lamid,
                                                     const int* __restrict__ cut,
                                                     const int* __restrict__ sortn,
                                                     float2* __restrict__ Spack) {
  int r = blockIdx.y;
  int n = sortn[r];
  int l = blockIdx.x * 256 + threadIdx.x;
  float sr = 0.f, si = 0.f;
  if (l < cut[n]) {
    float mag = expf(lamr[n] * (float)l);
    double ph = lamid[n] * (double)l;
    const double tp = 6.283185307179586476925287;
    const double itp = 1.0 / 6.283185307179586476925287;
    ph -= floor(ph * itp) * tp;
    float cs, sn; sincosf((float)ph, &sn, &cs);
    sr = mag * cs; si = mag * sn;
  }
  Spack[(size_t)r * SLEN + l] = make_float2(sr, si);
}

// ---------------- KT[d,l] = sum_{r<nact} (Sr*Cr - Si*Ci), 8-deep prefetch ----------
// Grid: (DDIM/KB5_DT, NTILE) — d-group is the FAST blockIdx dim so the heavy
// t=0 blocks (ids 0..255) round-robin across all 8 XCDs. (Round-10 lesson.)
#define KB5_DT 4
__global__ __launch_bounds__(256) void kbuild7_kernel(const float2* __restrict__ Spack,
                                                      const float2* __restrict__ Cpk,
                                                      const int* __restrict__ tcount,
                                                      float* __restrict__ KT) {
  __shared__ float2 sC[NMODE][KB5_DT];
  int t = blockIdx.y;
  int d0 = blockIdx.x * KB5_DT;
  int tid = threadIdx.x;
  int nact = tcount[t];
  for (int i = tid; i < nact * KB5_DT; i += 256) {
    int r = i >> 2, dd = i & 3;
    sC[r][dd] = Cpk[(size_t)r * DDIM + d0 + dd];
  }
  __syncthreads();
  int l = t * KB4_LT + tid;
  float acc0 = 0.f, acc1 = 0.f, acc2 = 0.f, acc3 = 0.f;
  const float2* sp = Spack + l;
  int i = 0;
  int n8 = nact & ~7;
  for (; i < n8; i += 8) {
    const float2* p = sp + (size_t)i * SLEN;
    float2 s0 = p[0];
    float2 s1 = p[(size_t)1 * SLEN];
    float2 s2 = p[(size_t)2 * SLEN];
    float2 s3 = p[(size_t)3 * SLEN];
    float2 s4 = p[(size_t)4 * SLEN];
    float2 s5 = p[(size_t)5 * SLEN];
    float2 s6 = p[(size_t)6 * SLEN];
    float2 s7 = p[(size_t)7 * SLEN];
    #define KACC(ss, rr) { \
      float2 c0 = sC[rr][0], c1 = sC[rr][1], c2 = sC[rr][2], c3 = sC[rr][3]; \
      acc0 += ss.x * c0.x - ss.y * c0.y; \
      acc1 += ss.x * c1.x - ss.y * c1.y; \
      acc2 += ss.x * c2.x - ss.y * c2.y; \
      acc3 += ss.x * c3.x - ss.y * c3.y; }
    KACC(s0, i + 0) KACC(s1, i + 1) KACC(s2, i + 2) KACC(s3, i + 3)
    KACC(s4, i + 4) KACC(s5, i + 5) KACC(s6, i + 6) KACC(s7, i + 7)
  }
  for (; i < nact; ++i) {
    float2 s0 = sp[(size_t)i * SLEN];
    KACC(s0, i)
  }
  #undef KACC
  KT[(size_t)(d0 + 0) * SLEN + l] = acc0;
  KT[(size_t)(d0 + 1) * SLEN + l] = acc1;
  KT[(size_t)(d0 + 2) * SLEN + l] = acc2;
  KT[(size_t)(d0 + 3) * SLEN + l] = acc3;
}

// ================= radix-8 building blocks (verified algebra, rounds 11-16) =================
// R4BLK: verified radix-4 block. Inputs b0,b2,b1,b3; twiddles wa, wb; outputs o0..o3.
#define R4BLK(b0, b2, b1, b3, wa, wb, o0, o1, o2, o3) { \
  float war=(wa).x, wai=sign*(wa).y, wbr=(wb).x, wbi=sign*(wb).y; \
  float t1r_=war*(b2).x - wai*(b2).y, t1i_=war*(b2).y + wai*(b2).x; \
  float t3r_=war*(b3).x - wai*(b3).y, t3i_=war*(b3).y + wai*(b3).x; \
  float Ar=(b0).x+t1r_, Ai=(b0).y+t1i_, Cr=(b0).x-t1r_, Ci=(b0).y-t1i_; \
  float Br=(b1).x+t3r_, Bi=(b1).y+t3i_, Dr=(b1).x-t3r_, Di=(b1).y-t3i_; \
  float Er=wbr*Br-wbi*Bi, Ei=wbr*Bi+wbi*Br; \
  float Fr=wbr*Dr-wbi*Di, Fi=wbr*Di+wbi*Dr; \
  dst[PIDX(o0)]=make_float2(Ar+Er,Ai+Ei); \
  dst[PIDX(o1)]=make_float2(Cr-sign*Fi,Ci+sign*Fr); \
  dst[PIDX(o2)]=make_float2(Ar-Er,Ai-Ei); \
  dst[PIDX(o3)]=make_float2(Cr+sign*Fi,Ci-sign*Fr); }

// stage-0 twiddle constants: twH[1]=twH[2]=twH[4]=(1,0), twH[3]=(0,1), twH[5]=(r2,r2)
#define TW_1 make_float2(1.f, 0.f)
#define TW_I make_float2(0.f, 1.f)
#define TW_Q make_float2(0.70710678118654752f, 0.70710678118654752f)

// IN-PLACE radix-8 stage, 512 threads x 2 butterflies: read 16 + level-1 into
// regs, barrier, write 16. Caller must __syncthreads() after.
__device__ __forceinline__ void r8_stage_ip2(float2* buf, const float2* __restrict__ twH,
                                             int tid, float sign, int s) {
  int L = 1 << s;
  int j0 = tid, j1 = tid + 512;
  int p0 = j0 & (L - 1), q0 = j0 >> s;
  int p1 = j1 & (L - 1), q1 = j1 >> s;
  float2 xa0 = buf[PIDX(j0)];
  float2 xa1 = buf[PIDX(j0 + 1024)];
  float2 xa2 = buf[PIDX(j0 + 2048)];
  float2 xa3 = buf[PIDX(j0 + 3072)];
  float2 xa4 = buf[PIDX(j0 + 4096)];
  float2 xa5 = buf[PIDX(j0 + 5120)];
  float2 xa6 = buf[PIDX(j0 + 6144)];
  float2 xa7 = buf[PIDX(j0 + 7168)];
  float2 xb0 = buf[PIDX(j1)];
  float2 xb1 = buf[PIDX(j1 + 1024)];
  float2 xb2 = buf[PIDX(j1 + 2048)];
  float2 xb3 = buf[PIDX(j1 + 3072)];
  float2 xb4 = buf[PIDX(j1 + 4096)];
  float2 xb5 = buf[PIDX(j1 + 5120)];
  float2 xb6 = buf[PIDX(j1 + 6144)];
  float2 xb7 = buf[PIDX(j1 + 7168)];
  float2 wA = twH[L + p0], wB = twH[L + p1];
  float2 A0, A1, A2, A3, B0, B1, B2, B3;
  {
    float wr = wA.x, wi = sign * wA.y;
    float t4r = wr*xa4.x - wi*xa4.y, t4i = wr*xa4.y + wi*xa4.x;
    float t5r = wr*xa5.x - wi*xa5.y, t5i = wr*xa5.y + wi*xa5.x;
    float t6r = wr*xa6.x - wi*xa6.y, t6i = wr*xa6.y + wi*xa6.x;
    float t7r = wr*xa7.x - wi*xa7.y, t7i = wr*xa7.y + wi*xa7.x;
    A0 = make_float2(xa0.x + t4r, xa0.y + t4i); B0 = make_float2(xa0.x - t4r, xa0.y - t4i);
    A1 = make_float2(xa1.x + t5r, xa1.y + t5i); B1 = make_float2(xa1.x - t5r, xa1.y - t5i);
    A2 = make_float2(xa2.x + t6r, xa2.y + t6i); B2 = make_float2(xa2.x - t6r, xa2.y - t6i);
    A3 = make_float2(xa3.x + t7r, xa3.y + t7i); B3 = make_float2(xa3.x - t7r, xa3.y - t7i);
  }
  float2 C0, C1, C2, C3, D0, D1, D2, D3;
  {
    float wr = wB.x, wi = sign * wB.y;
    float t4r = wr*xb4.x - wi*xb4.y, t4i = wr*xb4.y + wi*xb4.x;
    float t5r = wr*xb5.x - wi*xb5.y, t5i = wr*xb5.y + wi*xb5.x;
    float t6r = wr*xb6.x - wi*xb6.y, t6i = wr*xb6.y + wi*xb6.x;
    float t7r = wr*xb7.x - wi*xb7.y, t7i = wr*xb7.y + wi*xb7.x;
    C0 = make_float2(xb0.x + t4r, xb0.y + t4i); D0 = make_float2(xb0.x - t4r, xb0.y - t4i);
    C1 = make_float2(xb1.x + t5r, xb1.y + t5i); D1 = make_float2(xb1.x - t5r, xb1.y - t5i);
    C2 = make_float2(xb2.x + t6r, xb2.y + t6i); D2 = make_float2(xb2.x - t6r, xb2.y - t6i);
    C3 = make_float2(xb3.x + t7r, xb3.y + t7i); D3 = make_float2(xb3.x - t7r, xb3.y - t7i);
  }
  __syncthreads();           // all reads complete before any writes
  float2* dst = buf;
  int O0 = (q0 << (s + 3)) + p0;
  R4BLK(A0, A2, A1, A3, twH[2*L + p0], twH[4*L + p0], O0, O0 + 2*L, O0 + 4*L, O0 + 6*L)
  R4BLK(B0, B2, B1, B3, twH[3*L + p0], twH[5*L + p0], O0 + L, O0 + 3*L, O0 + 5*L, O0 + 7*L)
  int O1 = (q1 << (s + 3)) + p1;
  R4BLK(C0, C2, C1, C3, twH[2*L + p1], twH[4*L + p1], O1, O1 + 2*L, O1 + 4*L, O1 + 6*L)
  R4BLK(D0, D2, D1, D3, twH[3*L + p1], twH[5*L + p1], O1 + L, O1 + 3*L, O1 + 5*L, O1 + 7*L)
}

// fused forward-final-radix-2: Z[k] and Z[8192-k] from pre-final state s[] (1<=k<=4095).
__device__ __forceinline__ void fwd_final_pair(const float2* sbuf, const float2* __restrict__ twH,
                                               int k, float2* zk, float2* zm) {
  float2 a1 = sbuf[PIDX(k)], b1 = sbuf[PIDX(k + 4096)];
  float2 w1 = twH[4096 + k];
  float br1 = w1.x*b1.x + w1.y*b1.y;   // sign=-1: w_eff = (w.x, -w.y)
  float bi1 = w1.x*b1.y - w1.y*b1.x;
  *zk = make_float2(a1.x + br1, a1.y + bi1);
  float2 a2 = sbuf[PIDX(4096 - k)], b2 = sbuf[PIDX(8192 - k)];
  float2 w2 = twH[8192 - k];
  float br2 = w2.x*b2.x + w2.y*b2.y;
  float bi2 = w2.x*b2.y - w2.y*b2.x;
  *zm = make_float2(a2.x - br2, a2.y - bi2);
}

// Hermitian split + spectral multiply + inverse-repack for conjugate pair (k, 8192-k)
__device__ __forceinline__ void pw_pair(float2 zk, float2 zm, int k,
                                        const float2* __restrict__ twR,
                                        const float2* __restrict__ kf,
                                        float2* outk, float2* outm) {
  float Ar = 0.5f * (zk.x + zm.x), Ai = 0.5f * (zk.y - zm.y);
  float Br = 0.5f * (zk.x - zm.x), Bi = 0.5f * (zk.y + zm.y);
  float2 t = twR[k];
  float c = t.x, sn = t.y;
  float e1r = sn * Br - c * Bi;
  float e1i = sn * Bi + c * Br;
  float Ukr = Ar - e1r, Uki = Ai - e1i;      // U[k]
  float Umr = Ar + e1r, Umi = -Ai - e1i;     // U[8192-k]
  float2 kk = kf[k], km = kf[MFFT - k];
  float Ykr = Ukr * kk.x - Uki * kk.y, Yki = Ukr * kk.y + Uki * kk.x;
  float Ymr = Umr * km.x - Umi * km.y, Ymi = Umr * km.y + Umi * km.x;
  float Eyr = 0.5f * (Ykr + Ymr), Eyi = 0.5f * (Yki - Ymi);
  float Byr = 0.5f * (Ykr - Ymr), Byi = 0.5f * (Yki + Ymi);
  *outk = make_float2(Eyr - sn * Byr - c * Byi, Eyi + c * Byr - sn * Byi);
  *outm = make_float2(Eyr + sn * Byr + c * Byi, -Eyi + c * Byr - sn * Byi);
}

__device__ __forceinline__ void pw_compute(const float2* buf, const float2* __restrict__ twH,
                                           const float2* __restrict__ twR,
                                           const float2* __restrict__ kf,
                                           int k, float2* outk, float2* outm) {
  float2 zk, zm;
  fwd_final_pair(buf, twH, k, &zk, &zm);
  pw_pair(zk, zm, k, twR, kf, outk, outm);
}

// ---------------- Kf[d,k] = rfft16384(K_T[d]) / 8192, k=0..8192 ----------------
__global__ __launch_bounds__(512, 4) void kf_fft_kernel(const float* __restrict__ KT,
                                                        const float2* __restrict__ twH,
                                                        const float2* __restrict__ twR,
                                                        float2* __restrict__ Kf) {
  __shared__ float2 buf[FBUF];
  int d = blockIdx.x;
  int tid = threadIdx.x;
  const float2* row = (const float2*)(KT + (size_t)d * SLEN);   // 2048 float2
  const float sign = -1.f;
  {   // first radix-8 stage fused with global load (inputs 2048.. are zero)
    float2* dst = buf;
    #pragma unroll
    for (int i = 0; i < 2; ++i) {
      int j = tid + 512 * i;
      float2 x0 = row[j];
      float2 x1 = row[j + 1024];
      float2 zf = make_float2(0.f, 0.f);
      int O = j << 3;
      R4BLK(x0, zf, x1, zf, TW_1, TW_1, O, O + 2, O + 4, O + 6)
      R4BLK(x0, zf, x1, zf, TW_I, TW_Q, O + 1, O + 3, O + 5, O + 7)
    }
  }
  __syncthreads();
  r8_stage_ip2(buf, twH, tid, sign, 3);
  __syncthreads();
  r8_stage_ip2(buf, twH, tid, sign, 6);
  __syncthreads();
  r8_stage_ip2(buf, twH, tid, sign, 9);
  __syncthreads();
  // fused final radix-2 + Hermitian split + scale -> global (read-only on buf)
  const float scale = 1.0f / 8192.0f;         // fold inverse-FFT 1/8192 here
  float2* out = Kf + (size_t)d * KF_STRIDE;
  for (int k = tid; k <= 4096; k += 512) {
    if (k == 0) {
      float2 s0 = buf[PIDX(0)], s4 = buf[PIDX(4096)];
      float2 z0 = make_float2(s0.x + s4.x, s0.y + s4.y);
      out[0]    = make_float2((z0.x + z0.y) * scale, 0.f);
      out[8192] = make_float2((z0.x - z0.y) * scale, 0.f);
    } else {
      float2 zk, zm;
      if (k == 4096) {
        float2 s0 = buf[PIDX(0)], s4 = buf[PIDX(4096)];
        zk = make_float2(s0.x - s4.x, s0.y - s4.y);
        zm = zk;
      } else {
        fwd_final_pair(buf, twH, k, &zk, &zm);
      }
      float Ar = 0.5f * (zk.x + zm.x), Ai = 0.5f * (zk.y - zm.y);
      float Br = 0.5f * (zk.x - zm.x), Bi = 0.5f * (zk.y + zm.y);
      float2 t = twR[k];
      float c = t.x, sn = t.y;
      float e1r = sn * Br - c * Bi;
      float e1i = sn * Bi + c * Br;
      out[k]        = make_float2((Ar - e1r) * scale, (Ai - e1i) * scale);
      out[MFFT - k] = make_float2((Ar + e1r) * scale, (-Ai - e1i) * scale);
    }
  }
}

// ---------------- conv: y = irfft(rfft(u) * Kf) + u*pD, in-place over uT row ----------------
// 512 threads x 2 butterflies, single 64KB swizzled LDS buffer, in place.
// 2 WGs/CU = 1024 threads, 128KB LDS — co-residency feasible (round-17 retry).
// Pointwise phases (closed read/write sets, verified):
//   A: {k, 4096-k} for k in [1,1024) plus {0, 4096}
//   B: {1024+t, 3072-t} for t in [0,1024) plus {2048}
__global__ __launch_bounds__(512, 4) void conv_fft_kernel(float* __restrict__ uT,
                                                          const float2* __restrict__ twH,
                                                          const float2* __restrict__ twR,
                                                          const float2* __restrict__ Kf,
                                                          const float* __restrict__ pD) {
  __shared__ float2 buf[FBUF];
  int wg = blockIdx.x;
  int b = wg >> 10, d = wg & (DDIM - 1);
  int tid = threadIdx.x;
  float2* row = (float2*)(uT + ((size_t)b * DDIM + d) * LLEN);  // 4096 float2 of u
  float sign = -1.f;
  const float2* kf = Kf + (size_t)d * KF_STRIDE;
  {   // first radix-8 stage fused with global load (inputs 4096.. are zero)
    float2* dst = buf;
    #pragma unroll
    for (int i = 0; i < 2; ++i) {
      int j = tid + 512 * i;
      float2 x0 = row[j];
      float2 x1 = row[j + 1024];
      float2 x2 = row[j + 2048];
      float2 x3 = row[j + 3072];
      int O = j << 3;   // x4..x7 = 0 -> A_m = B_m = x_m
      R4BLK(x0, x2, x1, x3, TW_1, TW_1, O, O + 2, O + 4, O + 6)
      R4BLK(x0, x2, x1, x3, TW_I, TW_Q, O + 1, O + 3, O + 5, O + 7)
    }
  }
  __syncthreads();
  r8_stage_ip2(buf, twH, tid, sign, 3);
  __syncthreads();
  r8_stage_ip2(buf, twH, tid, sign, 6);
  __syncthreads();
  r8_stage_ip2(buf, twH, tid, sign, 9);
  __syncthreads();
  // ---- pointwise phase A ----
  {
    float2 oA0_0, oA1_0, oB0_0, oB1_0;
    float2 oA0_1, oA1_1, oB0_1, oB1_1;
    if (tid == 0) {
      float2 s0 = buf[PIDX(0)], s4 = buf[PIDX(4096)];
      float2 z0 = make_float2(s0.x + s4.x, s0.y + s4.y);
      float U0 = z0.x + z0.y;
      float UM = z0.x - z0.y;
      float Y0 = U0 * kf[0].x;
      float YM = UM * kf[8192].x;
      oA0_0 = make_float2(0.5f * (Y0 + YM), 0.5f * (Y0 - YM));
      float2 zk = make_float2(s0.x - s4.x, s0.y - s4.y);   // k=4096 (self-conjugate)
      float2 dum;
      pw_pair(zk, zk, 4096, twR, kf, &oB0_0, &dum);
      oA1_0 = oB1_0 = make_float2(0.f, 0.f);
    } else {
      pw_compute(buf, twH, twR, kf, tid, &oA0_0, &oA1_0);
      pw_compute(buf, twH, twR, kf, 4096 - tid, &oB0_0, &oB1_0);
    }
    {
      int k = tid + 512;
      pw_compute(buf, twH, twR, kf, k, &oA0_1, &oA1_1);
      pw_compute(buf, twH, twR, kf, 4096 - k, &oB0_1, &oB1_1);
    }
    __syncthreads();
    if (tid == 0) {
      buf[PIDX(0)] = oA0_0;
      buf[PIDX(4096)] = oB0_0;
    } else {
      buf[PIDX(tid)] = oA0_0;        buf[PIDX(8192 - tid)] = oA1_0;
      buf[PIDX(4096 - tid)] = oB0_0; buf[PIDX(4096 + tid)] = oB1_0;
    }
    {
      int k = tid + 512;
      buf[PIDX(k)] = oA0_1;        buf[PIDX(8192 - k)] = oA1_1;
      buf[PIDX(4096 - k)] = oB0_1; buf[PIDX(4096 + k)] = oB1_1;
    }
    __syncthreads();
  }
  // ---- pointwise phase B ----
  {
    float2 oC0_0, oC1_0, oD0_0, oD1_0;
    float2 oC0_1, oC1_1, oD0_1, oD1_1;
    float2 oE0, oE1;
    int kC0 = 1024 + tid, kD0 = 3072 - tid;
    int kC1 = 1024 + tid + 512, kD1 = 3072 - tid - 512;
    pw_compute(buf, twH, twR, kf, kC0, &oC0_0, &oC1_0);
    pw_compute(buf, twH, twR, kf, kD0, &oD0_0, &oD1_0);
    pw_compute(buf, twH, twR, kf, kC1, &oC0_1, &oC1_1);
    pw_compute(buf, twH, twR, kf, kD1, &oD0_1, &oD1_1);
    if (tid == 0) pw_compute(buf, twH, twR, kf, 2048, &oE0, &oE1);
    __syncthreads();
    buf[PIDX(kC0)] = oC0_0; buf[PIDX(8192 - kC0)] = oC1_0;
    buf[PIDX(kD0)] = oD0_0; buf[PIDX(8192 - kD0)] = oD1_0;
    buf[PIDX(kC1)] = oC0_1; buf[PIDX(8192 - kC1)] = oC1_1;
    buf[PIDX(kD1)] = oD0_1; buf[PIDX(8192 - kD1)] = oD1_1;
    if (tid == 0) { buf[PIDX(2048)] = oE0; buf[PIDX(6144)] = oE1; }
    __syncthreads();
  }
  // ---- inverse FFT: 4 in-place radix-8 stages + fused final radix-2 in epilogue ----
  sign = +1.f;
  r8_stage_ip2(buf, twH, tid, sign, 0);
  __syncthreads();
  r8_stage_ip2(buf, twH, tid, sign, 3);
  __syncthreads();
  r8_stage_ip2(buf, twH, tid, sign, 6);
  __syncthreads();
  r8_stage_ip2(buf, twH, tid, sign, 9);
  __syncthreads();
  // fused inverse final radix-2 (only lower half needed) + residual -> global
  float pdv = pD[d];
  #pragma unroll
  for (int i = 0; i < 8; ++i) {
    int j = tid + 512 * i;
    float2 a = buf[PIDX(j)];
    float2 bq = buf[PIDX(j + 4096)];
    float2 w = twH[4096 + j];           // inv: wi = +w.y
    float br = w.x * bq.x - w.y * bq.y;
    float bi = w.x * bq.y + w.y * bq.x;
    float2 uv = row[j];                 // original u (untouched so far)
    row[j] = make_float2(a.x + br + uv.x * pdv, a.y + bi + uv.y * pdv);
  }
}

// ---------------- out[b,l,d] = yT[b,d,l] (transpose back) ----------------
__global__ __launch_bounds__(256) void final_kernel(const float* __restrict__ yT,
                                                    float* __restrict__ out) {
  __shared__ float tile[32][33];
  int lt = blockIdx.x * 32, dt = blockIdx.y * 32, b = blockIdx.z;
  int c = threadIdx.x & 31, r0 = threadIdx.x >> 5;
  #pragma unroll
  for (int i = 0; i < 4; i++) {
    int r = r0 + i * 8;   // d within tile
    tile[r][c] = yT[((size_t)b * DDIM + dt + r) * LLEN + lt + c];
  }
  __syncthreads();
  #pragma unroll
  for (int i = 0; i < 4; i++) {
    int r = r0 + i * 8;   // l within tile
    out[((size_t)b * LLEN + lt + r) * DDIM + dt + c] = tile[c][r];
  }
}

extern "C" void kernel_launch(void* const* d_in, const int* in_sizes, int n_in,
                              void* d_out, int out_size, void* d_ws, size_t ws_size,
                              hipStream_t stream) {
  (void)in_sizes; (void)n_in; (void)out_size;
  if (ws_size < WS_NEED) return;   // safety: fail cleanly (wrong output) instead of faulting
  const float* x     = (const float*)d_in[0];
  const float* Lr    = (const float*)d_in[1];
  const float* Li    = (const float*)d_in[2];
  const float* Cr    = (const float*)d_in[3];
  const float* Ci    = (const float*)d_in[4];
  const float* pD    = (const float*)d_in[5];
  const float* gamma = (const float*)d_in[6];
  const float* beta  = (const float*)d_in[7];
  float* out = (float*)d_out;
  char* ws = (char*)d_ws;

  float*  UT    = (float*)(ws + OFF_UT);
  float2* KF    = (float2*)(ws + OFF_KF);
  float2* SPK   = (float2*)(ws + OFF_SP);   // overlaid on KF region
  float*  KT    = (float*)(ws + OFF_KT);
  float2* CPK   = (float2*)(ws + OFF_CPK);
  float*  MEAN  = (float*)(ws + OFF_MEAN);
  float*  RSTD  = (float*)(ws + OFF_RSTD);
  float*  LAMR  = (float*)(ws + OFF_LAMR);
  double* LAMID = (double*)(ws + OFF_LAMID);
  float*  WRe   = (float*)(ws + OFF_WR);
  float*  WIm   = (float*)(ws + OFF_WI);
  int*    CUT   = (int*)(ws + OFF_CUT);
  float2* TWH   = (float2*)(ws + OFF_TW);
  float2* TWR   = (float2*)(ws + OFF_TWR);
  int*    SORTN = (int*)(ws + OFF_SORTN);
  int*    TCNT  = (int*)(ws + OFF_TCNT);

  ln_stats_kernel<<<NB * LLEN, 256, 0, stream>>>(x, MEAN, RSTD);
  transpose_ln_kernel<<<dim3(LLEN / 32, DDIM / 32, NB), 256, 0, stream>>>(x, MEAN, RSTD, gamma, beta, UT);
  build_tables_kernel<<<67, 256, 0, stream>>>(Lr, Li, LAMR, LAMID, WRe, WIm, CUT, TWH, TWR);
  sortmodes_kernel<<<1, NMODE, 0, stream>>>(CUT, SORTN, TCNT);
  cpack_kernel<<<(NMODE * DDIM) / 256, 256, 0, stream>>>(Cr, Ci, WRe, WIm, SORTN, CPK);
  sbuild_kernel<<<dim3(SLEN / 256, NMODE), 256, 0, stream>>>(LAMR, LAMID, CUT, SORTN, SPK);
  kbuild7_kernel<<<dim3(DDIM / KB5_DT, NTILE), 256, 0, stream>>>(SPK, CPK, TCNT, KT);
  kf_fft_kernel<<<DDIM, 512, 0, stream>>>(KT, TWH, TWR, KF);   // KF overwrites Spack (dead now)
  conv_fft_kernel<<<NB * DDIM, 512, 0, stream>>>(UT, TWH, TWR, KF, pD);
  final_kernel<<<dim3(LLEN / 32, DDIM / 32, NB), 256, 0, stream>>>(UT, out);
}

// Round 19
// 299.041 us; speedup vs baseline: 1.1888x; 1.1888x over previous
//
#include <hip/hip_runtime.h>
#include <math.h>

#define LLEN 8192
#define DDIM 1024
#define NB   2
#define NMODE 512
#define MFFT 8192
#define SLEN 4096        // truncated kernel length (K[l]=0 beyond; worst-case e^-20)
#define KF_STRIDE 8208   // float2 per Kf row (8193 used)

// XOR-swizzled LDS index (bijective), buffer exactly 64 KB.
#define PIDX(i) ((i) ^ (((i) >> 4) & 15))
#define FBUF 8192        // float2 per buffer = 65,536 B exactly

// ---------------- workspace layout (bytes), total ~172.4 MB ----------------
#define OFF_UT   ((size_t)0)            // u_T [B,D,L] f32 (y+res in place)  67,108,864
#define OFF_KF   ((size_t)67108864)     // Kf [D,KF_STRIDE] float2           67,239,936
#define OFF_KT   ((size_t)134348800)    // K_T [D][SLEN] f32                 16,777,216
#define OFF_CPK  ((size_t)167903232)    // Cpk [512][1024] float2             4,194,304
#define OFF_MEAN ((size_t)172097536)    // mean [B,L] f32                        65,536
#define OFF_RSTD ((size_t)172163072)    // rstd [B,L] f32                        65,536
#define OFF_LAMR ((size_t)172228608)    // f32[512]
#define OFF_LAMID ((size_t)172230656)   // f64[512] (4096 B)
#define OFF_WR   ((size_t)172234752)    // f32[512]
#define OFF_WI   ((size_t)172236800)    // f32[512]
#define OFF_CUT  ((size_t)172238848)    // int[512]
#define OFF_TW   ((size_t)172240896)    // twH: 8192 float2 (hierarchical)      65,536
#define OFF_TWR  ((size_t)172306432)    // 8193 float2 (2pi k/16384)            65,544
#define OFF_SORTN ((size_t)172371976)   // int[512] rank->mode                    2,048
#define OFF_TCNT  ((size_t)172374024)   // int[16] per-l-tile active prefix          64
#define WS_NEED  ((size_t)172374088)

// Spack overlay inside the KF region (dead until kf_fft writes KF)
#define OFF_SP   OFF_KF

// ---------------- LayerNorm stats: mean/rstd per (b,l) row ----------------
__global__ __launch_bounds__(256) void ln_stats_kernel(const float* __restrict__ x,
                                                       float* __restrict__ mean,
                                                       float* __restrict__ rstd) {
  __shared__ float red[16];
  int row = blockIdx.x;            // b*L + l
  int tid = threadIdx.x;
  const float4* xr = (const float4*)(x + (size_t)row * DDIM);
  float4 v = xr[tid];
  float s = v.x + v.y + v.z + v.w;
  float q = v.x*v.x + v.y*v.y + v.z*v.z + v.w*v.w;
  #pragma unroll
  for (int off = 32; off; off >>= 1) { s += __shfl_down(s, off); q += __shfl_down(q, off); }
  int wid = tid >> 6;
  if ((tid & 63) == 0) { red[wid] = s; red[8 + wid] = q; }
  __syncthreads();
  if (tid == 0) {
    float ts = red[0] + red[1] + red[2] + red[3];
    float tq = red[8] + red[9] + red[10] + red[11];
    float m = ts * (1.0f / DDIM);
    float var = tq * (1.0f / DDIM) - m * m;
    mean[row] = m;
    rstd[row] = rsqrtf(var + 1e-5f);
  }
}

// ---------------- fused LN + transpose: x[B,L,D] -> uT[B,D,L] ----------------
__global__ __launch_bounds__(256) void transpose_ln_kernel(const float* __restrict__ x,
                                                           const float* __restrict__ mean,
                                                           const float* __restrict__ rstd,
                                                           const float* __restrict__ gamma,
                                                           const float* __restrict__ beta,
                                                           float* __restrict__ uT) {
  __shared__ float tile[32][33];
  int lt = blockIdx.x * 32, dt = blockIdx.y * 32, b = blockIdx.z;
  int c = threadIdx.x & 31, r0 = threadIdx.x >> 5;
  float gv = gamma[dt + c], bv = beta[dt + c];
  #pragma unroll
  for (int i = 0; i < 4; i++) {
    int r = r0 + i * 8;   // l within tile
    float m = mean[(size_t)b * LLEN + lt + r];
    float rs = rstd[(size_t)b * LLEN + lt + r];
    float xv = x[((size_t)b * LLEN + lt + r) * DDIM + dt + c];
    tile[r][c] = (xv - m) * rs * gv + bv;
  }
  __syncthreads();
  #pragma unroll
  for (int i = 0; i < 4; i++) {
    int r = r0 + i * 8;   // d within tile
    uT[((size_t)b * DDIM + dt + r) * LLEN + lt + c] = tile[c][r];
  }
}

// ---------------- params + twiddle tables (all one-time, double precision) ----------------
__global__ void build_tables_kernel(const float* __restrict__ Lr, const float* __restrict__ Li,
                                    float* lamr, double* lamid, float* wre, float* wim, int* cut,
                                    float2* twH, float2* twR) {
  int gid = blockIdx.x * 256 + threadIdx.x;
  if (gid < NMODE) {
    double lr = (double)Lr[gid], li = (double)Li[gid];
    double ar = -exp(lr);      // Re(Lam)  (negative)
    double ai = exp(li);       // Im(Lam)
    lamr[gid] = (float)ar;
    lamid[gid] = ai;
    double em = exp(ar);
    double cs = cos(ai), sn = sin(ai);
    double er = em * cs - 1.0;     // exp(Lam) - 1
    double ei = em * sn;
    double den = ar * ar + ai * ai;
    wre[gid] = (float)((er * ar + ei * ai) / den);   // (exp(Lam)-1)/Lam
    wim[gid] = (float)((ei * ar - er * ai) / den);
    int co = (int)(40.0 / (-ar)) + 1;                // exp(ar*l) < e^-40 beyond
    cut[gid] = co > SLEN ? SLEN : co;                // clamp to truncated domain
  }
  int j = gid - NMODE;
  if (j >= 0 && j < 8192) {
    // hierarchical twiddle: twH[Ls + p] = (cos(pi*p/Ls), +sin(pi*p/Ls)).
    // Applied as (w.x, sign*w.y): sign=-1 (fwd) -> e^{-i a}, sign=+1 (inv) -> e^{+i a}.
    if (j == 0) {
      twH[0] = make_float2(1.f, 0.f);
    } else {
      int lev = 31 - __clz(j);
      int Ls = 1 << lev;
      int p = j - Ls;
      double a = 3.14159265358979323846264338 * (double)p / (double)Ls;
      twH[j] = make_float2((float)cos(a), (float)sin(a));
    }
  }
  int k = gid - (NMODE + 8192);
  if (k >= 0 && k <= 8192) {
    double a = 6.283185307179586476925287 * (double)k / 16384.0;
    twR[k] = make_float2((float)cos(a), (float)sin(a));
  }
}

// ---------------- sort modes by cut descending (rank), per-tile prefix counts ----------------
#define KB4_LT 256
#define NTILE (SLEN / KB4_LT)   // 16
__global__ __launch_bounds__(NMODE) void sortmodes_kernel(const int* __restrict__ cut,
                                                          int* __restrict__ sortn,
                                                          int* __restrict__ tcount) {
  __shared__ int sc[NMODE];
  int tid = threadIdx.x;
  sc[tid] = cut[tid];
  __syncthreads();
  int c = sc[tid];
  int rank = 0;
  for (int m = 0; m < NMODE; ++m) {
    int cm = sc[m];
    rank += (cm > c) || (cm == c && m < tid);
  }
  sortn[rank] = tid;
  if (tid < NTILE) {
    int l0 = tid * KB4_LT;
    int cnt = 0;
    for (int m = 0; m < NMODE; ++m) cnt += (sc[m] > l0);
    tcount[tid] = cnt;
  }
}

// ---------------- Cpk[r][d] = (Cr[d][n]+i Ci[d][n]) * W[n], n = sortn[r] ----------------
__global__ __launch_bounds__(256) void cpack_kernel(const float* __restrict__ Cr,
                                                    const float* __restrict__ Ci,
                                                    const float* __restrict__ wre,
                                                    const float* __restrict__ wim,
                                                    const int* __restrict__ sortn,
                                                    float2* __restrict__ Cpk) {
  int idx = blockIdx.x * 256 + threadIdx.x;   // r*D + d  (d fastest -> coalesced writes)
  int r = idx >> 10, d = idx & (DDIM - 1);
  int n = sortn[r];
  float cr = Cr[(size_t)d * NMODE + n], ci = Ci[(size_t)d * NMODE + n];
  float wr = wre[n], wi = wim[n];
  Cpk[idx] = make_float2(cr * wr - ci * wi, cr * wi + ci * wr);
}

// ---------------- Spack[r][l] = exp(Lam_{sortn[r]} l), zero beyond cut ----------------
__global__ __launch_bounds__(256) void sbuild_kernel(const float* __restrict__ lamr,
                                                     const double* __restrict__ lamid,
                                                     const int* __restrict__ cut,
                                                     const int* __restrict__ sortn,
                                                     float2* __restrict__ Spack) {
  int r = blockIdx.y;
  int n = sortn[r];
  int l = blockIdx.x * 256 + threadIdx.x;
  float sr = 0.f, si = 0.f;
  if (l < cut[n]) {
    float mag = expf(lamr[n] * (float)l);
    double ph = lamid[n] * (double)l;
    const double tp = 6.283185307179586476925287;
    const double itp = 1.0 / 6.283185307179586476925287;
    ph -= floor(ph * itp) * tp;
    float cs, sn; sincosf((float)ph, &sn, &cs);
    sr = mag * cs; si = mag * sn;
  }
  Spack[(size_t)r * SLEN + l] = make_float2(sr, si);
}

// ---------------- KT[d,l] = sum_{r<nact} (Sr*Cr - Si*Ci), 8-deep prefetch ----------
// Grid: (DDIM/KB5_DT, NTILE) — d-group is the FAST blockIdx dim so the heavy
// t=0 blocks (ids 0..255) round-robin across all 8 XCDs. (Round-10 lesson.)
#define KB5_DT 4
__global__ __launch_bounds__(256) void kbuild7_kernel(const float2* __restrict__ Spack,
                                                      const float2* __restrict__ Cpk,
                                                      const int* __restrict__ tcount,
                                                      float* __restrict__ KT) {
  __shared__ float2 sC[NMODE][KB5_DT];
  int t = blockIdx.y;
  int d0 = blockIdx.x * KB5_DT;
  int tid = threadIdx.x;
  int nact = tcount[t];
  for (int i = tid; i < nact * KB5_DT; i += 256) {
    int r = i >> 2, dd = i & 3;
    sC[r][dd] = Cpk[(size_t)r * DDIM + d0 + dd];
  }
  __syncthreads();
  int l = t * KB4_LT + tid;
  float acc0 = 0.f, acc1 = 0.f, acc2 = 0.f, acc3 = 0.f;
  const float2* sp = Spack + l;
  int i = 0;
  int n8 = nact & ~7;
  for (; i < n8; i += 8) {
    const float2* p = sp + (size_t)i * SLEN;
    float2 s0 = p[0];
    float2 s1 = p[(size_t)1 * SLEN];
    float2 s2 = p[(size_t)2 * SLEN];
    float2 s3 = p[(size_t)3 * SLEN];
    float2 s4 = p[(size_t)4 * SLEN];
    float2 s5 = p[(size_t)5 * SLEN];
    float2 s6 = p[(size_t)6 * SLEN];
    float2 s7 = p[(size_t)7 * SLEN];
    #define KACC(ss, rr) { \
      float2 c0 = sC[rr][0], c1 = sC[rr][1], c2 = sC[rr][2], c3 = sC[rr][3]; \
      acc0 += ss.x * c0.x - ss.y * c0.y; \
      acc1 += ss.x * c1.x - ss.y * c1.y; \
      acc2 += ss.x * c2.x - ss.y * c2.y; \
      acc3 += ss.x * c3.x - ss.y * c3.y; }
    KACC(s0, i + 0) KACC(s1, i + 1) KACC(s2, i + 2) KACC(s3, i + 3)
    KACC(s4, i + 4) KACC(s5, i + 5) KACC(s6, i + 6) KACC(s7, i + 7)
  }
  for (; i < nact; ++i) {
    float2 s0 = sp[(size_t)i * SLEN];
    KACC(s0, i)
  }
  #undef KACC
  KT[(size_t)(d0 + 0) * SLEN + l] = acc0;
  KT[(size_t)(d0 + 1) * SLEN + l] = acc1;
  KT[(size_t)(d0 + 2) * SLEN + l] = acc2;
  KT[(size_t)(d0 + 3) * SLEN + l] = acc3;
}

// ================= radix-8 building blocks (verified algebra, rounds 11-16) =================
// R4BLK: verified radix-4 block. Inputs b0,b2,b1,b3; twiddles wa, wb; outputs o0..o3.
#define R4BLK(b0, b2, b1, b3, wa, wb, o0, o1, o2, o3) { \
  float war=(wa).x, wai=sign*(wa).y, wbr=(wb).x, wbi=sign*(wb).y; \
  float t1r_=war*(b2).x - wai*(b2).y, t1i_=war*(b2).y + wai*(b2).x; \
  float t3r_=war*(b3).x - wai*(b3).y, t3i_=war*(b3).y + wai*(b3).x; \
  float Ar=(b0).x+t1r_, Ai=(b0).y+t1i_, Cr=(b0).x-t1r_, Ci=(b0).y-t1i_; \
  float Br=(b1).x+t3r_, Bi=(b1).y+t3i_, Dr=(b1).x-t3r_, Di=(b1).y-t3i_; \
  float Er=wbr*Br-wbi*Bi, Ei=wbr*Bi+wbi*Br; \
  float Fr=wbr*Dr-wbi*Di, Fi=wbr*Di+wbi*Dr; \
  dst[PIDX(o0)]=make_float2(Ar+Er,Ai+Ei); \
  dst[PIDX(o1)]=make_float2(Cr-sign*Fi,Ci+sign*Fr); \
  dst[PIDX(o2)]=make_float2(Ar-Er,Ai-Ei); \
  dst[PIDX(o3)]=make_float2(Cr+sign*Fi,Ci-sign*Fr); }

// stage-0 twiddle constants: twH[1]=twH[2]=twH[4]=(1,0), twH[3]=(0,1), twH[5]=(r2,r2)
#define TW_1 make_float2(1.f, 0.f)
#define TW_I make_float2(0.f, 1.f)
#define TW_Q make_float2(0.70710678118654752f, 0.70710678118654752f)

// DOUBLE-BUFFER radix-8 stage (src != dst): 1024 threads x 1 butterfly,
// ONE barrier per stage (caller syncs after). Round-18 lesson: anything
// holding >8 float2 across a barrier spills at this occupancy shape.
__device__ __forceinline__ void r8_stage(const float2* src, float2* dst,
                                         const float2* __restrict__ twH,
                                         int tid, float sign, int s) {
  int L = 1 << s;
  int j = tid;
  int p = j & (L - 1);
  int q = j >> s;
  float2 x0 = src[PIDX(j)];
  float2 x1 = src[PIDX(j + 1024)];
  float2 x2 = src[PIDX(j + 2048)];
  float2 x3 = src[PIDX(j + 3072)];
  float2 x4 = src[PIDX(j + 4096)];
  float2 x5 = src[PIDX(j + 5120)];
  float2 x6 = src[PIDX(j + 6144)];
  float2 x7 = src[PIDX(j + 7168)];
  float2 w1 = twH[L + p];
  float w1r = w1.x, w1i = sign * w1.y;
  float t4r = w1r*x4.x - w1i*x4.y, t4i = w1r*x4.y + w1i*x4.x;
  float t5r = w1r*x5.x - w1i*x5.y, t5i = w1r*x5.y + w1i*x5.x;
  float t6r = w1r*x6.x - w1i*x6.y, t6i = w1r*x6.y + w1i*x6.x;
  float t7r = w1r*x7.x - w1i*x7.y, t7i = w1r*x7.y + w1i*x7.x;
  float2 A0 = make_float2(x0.x + t4r, x0.y + t4i), B0 = make_float2(x0.x - t4r, x0.y - t4i);
  float2 A1 = make_float2(x1.x + t5r, x1.y + t5i), B1 = make_float2(x1.x - t5r, x1.y - t5i);
  float2 A2 = make_float2(x2.x + t6r, x2.y + t6i), B2 = make_float2(x2.x - t6r, x2.y - t6i);
  float2 A3 = make_float2(x3.x + t7r, x3.y + t7i), B3 = make_float2(x3.x - t7r, x3.y - t7i);
  int O = (q << (s + 3)) + p;
  R4BLK(A0, A2, A1, A3, twH[2*L + p], twH[4*L + p], O, O + 2*L, O + 4*L, O + 6*L)
  R4BLK(B0, B2, B1, B3, twH[3*L + p], twH[5*L + p], O + L, O + 3*L, O + 5*L, O + 7*L)
}

// fused forward-final-radix-2: Z[k] and Z[8192-k] from pre-final state s[] (1<=k<=4095).
__device__ __forceinline__ void fwd_final_pair(const float2* sbuf, const float2* __restrict__ twH,
                                               int k, float2* zk, float2* zm) {
  float2 a1 = sbuf[PIDX(k)], b1 = sbuf[PIDX(k + 4096)];
  float2 w1 = twH[4096 + k];
  float br1 = w1.x*b1.x + w1.y*b1.y;   // sign=-1: w_eff = (w.x, -w.y)
  float bi1 = w1.x*b1.y - w1.y*b1.x;
  *zk = make_float2(a1.x + br1, a1.y + bi1);
  float2 a2 = sbuf[PIDX(4096 - k)], b2 = sbuf[PIDX(8192 - k)];
  float2 w2 = twH[8192 - k];
  float br2 = w2.x*b2.x + w2.y*b2.y;
  float bi2 = w2.x*b2.y - w2.y*b2.x;
  *zm = make_float2(a2.x - br2, a2.y - bi2);
}

// Hermitian split + spectral multiply + inverse-repack for conjugate pair (k, 8192-k)
__device__ __forceinline__ void pw_pair(float2 zk, float2 zm, int k,
                                        const float2* __restrict__ twR,
                                        const float2* __restrict__ kf,
                                        float2* outk, float2* outm) {
  float Ar = 0.5f * (zk.x + zm.x), Ai = 0.5f * (zk.y - zm.y);
  float Br = 0.5f * (zk.x - zm.x), Bi = 0.5f * (zk.y + zm.y);
  float2 t = twR[k];
  float c = t.x, sn = t.y;
  float e1r = sn * Br - c * Bi;
  float e1i = sn * Bi + c * Br;
  float Ukr = Ar - e1r, Uki = Ai - e1i;      // U[k]
  float Umr = Ar + e1r, Umi = -Ai - e1i;     // U[8192-k]
  float2 kk = kf[k], km = kf[MFFT - k];
  float Ykr = Ukr * kk.x - Uki * kk.y, Yki = Ukr * kk.y + Uki * kk.x;
  float Ymr = Umr * km.x - Umi * km.y, Ymi = Umr * km.y + Umi * km.x;
  float Eyr = 0.5f * (Ykr + Ymr), Eyi = 0.5f * (Yki - Ymi);
  float Byr = 0.5f * (Ykr - Ymr), Byi = 0.5f * (Yki + Ymi);
  *outk = make_float2(Eyr - sn * Byr - c * Byi, Eyi + c * Byr - sn * Byi);
  *outm = make_float2(Eyr + sn * Byr + c * Byi, -Eyi + c * Byr - sn * Byi);
}

// ---------------- Kf[d,k] = rfft16384(K_T[d]) / 8192, k=0..8192 ----------------
__global__ __launch_bounds__(1024, 4) void kf_fft_kernel(const float* __restrict__ KT,
                                                         const float2* __restrict__ twH,
                                                         const float2* __restrict__ twR,
                                                         float2* __restrict__ Kf) {
  __shared__ float2 bufA[FBUF];
  __shared__ float2 bufB[FBUF];
  int d = blockIdx.x;
  int tid = threadIdx.x;
  const float2* row = (const float2*)(KT + (size_t)d * SLEN);   // 2048 float2
  const float sign = -1.f;
  {   // first radix-8 stage fused with global load (inputs 2048.. are zero) -> bufA
    float2* dst = bufA;
    float2 x0 = row[tid];
    float2 x1 = row[tid + 1024];
    float2 zf = make_float2(0.f, 0.f);
    int O = tid << 3;
    R4BLK(x0, zf, x1, zf, TW_1, TW_1, O, O + 2, O + 4, O + 6)
    R4BLK(x0, zf, x1, zf, TW_I, TW_Q, O + 1, O + 3, O + 5, O + 7)
  }
  __syncthreads();
  r8_stage(bufA, bufB, twH, tid, sign, 3);
  __syncthreads();
  r8_stage(bufB, bufA, twH, tid, sign, 6);
  __syncthreads();
  r8_stage(bufA, bufB, twH, tid, sign, 9);
  __syncthreads();
  // fused final radix-2 + Hermitian split + scale -> global (reads bufB only)
  const float scale = 1.0f / 8192.0f;         // fold inverse-FFT 1/8192 here
  float2* out = Kf + (size_t)d * KF_STRIDE;
  for (int k = tid; k <= 4096; k += 1024) {
    if (k == 0) {
      float2 s0 = bufB[PIDX(0)], s4 = bufB[PIDX(4096)];
      float2 z0 = make_float2(s0.x + s4.x, s0.y + s4.y);
      out[0]    = make_float2((z0.x + z0.y) * scale, 0.f);
      out[8192] = make_float2((z0.x - z0.y) * scale, 0.f);
    } else {
      float2 zk, zm;
      if (k == 4096) {
        float2 s0 = bufB[PIDX(0)], s4 = bufB[PIDX(4096)];
        zk = make_float2(s0.x - s4.x, s0.y - s4.y);
        zm = zk;
      } else {
        fwd_final_pair(bufB, twH, k, &zk, &zm);
      }
      float Ar = 0.5f * (zk.x + zm.x), Ai = 0.5f * (zk.y - zm.y);
      float Br = 0.5f * (zk.x - zm.x), Bi = 0.5f * (zk.y + zm.y);
      float2 t = twR[k];
      float c = t.x, sn = t.y;
      float e1r = sn * Br - c * Bi;
      float e1i = sn * Bi + c * Br;
      out[k]        = make_float2((Ar - e1r) * scale, (Ai - e1i) * scale);
      out[MFFT - k] = make_float2((Ar + e1r) * scale, (-Ai - e1i) * scale);
    }
  }
}

// ---------------- conv: y = irfft(rfft(u) * Kf) + u*pD, in-place over uT row ----------------
// Double-buffered (2 x 64KB swizzled LDS), ONE barrier per stage (9 total vs
// 17 in-place — rounds 13/16 showed occupancy is pinned at 1 WG/CU either way,
// so minimize barrier serialization instead). Pointwise is a single pass
// (src=bufB, dst=bufA — no closed-phase dance needed).
__global__ __launch_bounds__(1024, 4) void conv_fft_kernel(float* __restrict__ uT,
                                                           const float2* __restrict__ twH,
                                                           const float2* __restrict__ twR,
                                                           const float2* __restrict__ Kf,
                                                           const float* __restrict__ pD) {
  __shared__ float2 bufA[FBUF];
  __shared__ float2 bufB[FBUF];
  int wg = blockIdx.x;
  int b = wg >> 10, d = wg & (DDIM - 1);
  int tid = threadIdx.x;
  float2* row = (float2*)(uT + ((size_t)b * DDIM + d) * LLEN);  // 4096 float2 of u
  float sign = -1.f;
  const float2* kf = Kf + (size_t)d * KF_STRIDE;
  {   // first radix-8 stage fused with global load (inputs 4096.. are zero) -> bufA
    float2* dst = bufA;
    float2 x0 = row[tid];
    float2 x1 = row[tid + 1024];
    float2 x2 = row[tid + 2048];
    float2 x3 = row[tid + 3072];
    int O = tid << 3;   // x4..x7 = 0 -> A_m = B_m = x_m
    R4BLK(x0, x2, x1, x3, TW_1, TW_1, O, O + 2, O + 4, O + 6)
    R4BLK(x0, x2, x1, x3, TW_I, TW_Q, O + 1, O + 3, O + 5, O + 7)
  }
  __syncthreads();
  r8_stage(bufA, bufB, twH, tid, sign, 3);
  __syncthreads();
  r8_stage(bufB, bufA, twH, tid, sign, 6);
  __syncthreads();
  r8_stage(bufA, bufB, twH, tid, sign, 9);
  __syncthreads();
  // fused final radix-2 + Hermitian split + multiply + repack: bufB -> bufA (single pass)
  for (int k = tid; k <= 4096; k += 1024) {
    if (k == 0) {
      float2 s0 = bufB[PIDX(0)], s4 = bufB[PIDX(4096)];
      float2 z0 = make_float2(s0.x + s4.x, s0.y + s4.y);
      float U0 = z0.x + z0.y;
      float UM = z0.x - z0.y;
      float Y0 = U0 * kf[0].x;
      float YM = UM * kf[8192].x;
      bufA[PIDX(0)] = make_float2(0.5f * (Y0 + YM), 0.5f * (Y0 - YM));
    } else {
      float2 zk, zm;
      if (k == 4096) {
        float2 s0 = bufB[PIDX(0)], s4 = bufB[PIDX(4096)];
        zk = make_float2(s0.x - s4.x, s0.y - s4.y);
        zm = zk;
      } else {
        fwd_final_pair(bufB, twH, k, &zk, &zm);
      }
      float2 ok, om;
      pw_pair(zk, zm, k, twR, kf, &ok, &om);
      bufA[PIDX(k)] = ok;
      if (k != 4096) bufA[PIDX(MFFT - k)] = om;
    }
  }
  __syncthreads();
  // inverse FFT: 4 dbuf radix-8 stages + fused final radix-2 in epilogue
  sign = +1.f;
  r8_stage(bufA, bufB, twH, tid, sign, 0);
  __syncthreads();
  r8_stage(bufB, bufA, twH, tid, sign, 3);
  __syncthreads();
  r8_stage(bufA, bufB, twH, tid, sign, 6);
  __syncthreads();
  r8_stage(bufB, bufA, twH, tid, sign, 9);
  __syncthreads();
  // fused inverse final radix-2 (only lower half needed) + residual -> global
  float pdv = pD[d];
  for (int j = tid; j < 4096; j += 1024) {
    float2 a = bufA[PIDX(j)];
    float2 bq = bufA[PIDX(j + 4096)];
    float2 w = twH[4096 + j];           // inv: wi = +w.y
    float br = w.x * bq.x - w.y * bq.y;
    float bi = w.x * bq.y + w.y * bq.x;
    float2 uv = row[j];                 // original u (untouched so far)
    row[j] = make_float2(a.x + br + uv.x * pdv, a.y + bi + uv.y * pdv);
  }
}

// ---------------- out[b,l,d] = yT[b,d,l] (transpose back) ----------------
__global__ __launch_bounds__(256) void final_kernel(const float* __restrict__ yT,
                                                    float* __restrict__ out) {
  __shared__ float tile[32][33];
  int lt = blockIdx.x * 32, dt = blockIdx.y * 32, b = blockIdx.z;
  int c = threadIdx.x & 31, r0 = threadIdx.x >> 5;
  #pragma unroll
  for (int i = 0; i < 4; i++) {
    int r = r0 + i * 8;   // d within tile
    tile[r][c] = yT[((size_t)b * DDIM + dt + r) * LLEN + lt + c];
  }
  __syncthreads();
  #pragma unroll
  for (int i = 0; i < 4; i++) {
    int r = r0 + i * 8;   // l within tile
    out[((size_t)b * LLEN + lt + r) * DDIM + dt + c] = tile[c][r];
  }
}

extern "C" void kernel_launch(void* const* d_in, const int* in_sizes, int n_in,
                              void* d_out, int out_size, void* d_ws, size_t ws_size,
                              hipStream_t stream) {
  (void)in_sizes; (void)n_in; (void)out_size;
  if (ws_size < WS_NEED) return;   // safety: fail cleanly (wrong output) instead of faulting
  const float* x     = (const float*)d_in[0];
  const float* Lr    = (const float*)d_in[1];
  const float* Li    = (const float*)d_in[2];
  const float* Cr    = (const float*)d_in[3];
  const float* Ci    = (const float*)d_in[4];
  const float* pD    = (const float*)d_in[5];
  const float* gamma = (const float*)d_in[6];
  const float* beta  = (const float*)d_in[7];
  float* out = (float*)d_out;
  char* ws = (char*)d_ws;

  float*  UT    = (float*)(ws + OFF_UT);
  float2* KF    = (float2*)(ws + OFF_KF);
  float2* SPK   = (float2*)(ws + OFF_SP);   // overlaid on KF region
  float*  KT    = (float*)(ws + OFF_KT);
  float2* CPK   = (float2*)(ws + OFF_CPK);
  float*  MEAN  = (float*)(ws + OFF_MEAN);
  float*  RSTD  = (float*)(ws + OFF_RSTD);
  float*  LAMR  = (float*)(ws + OFF_LAMR);
  double* LAMID = (double*)(ws + OFF_LAMID);
  float*  WRe   = (float*)(ws + OFF_WR);
  float*  WIm   = (float*)(ws + OFF_WI);
  int*    CUT   = (int*)(ws + OFF_CUT);
  float2* TWH   = (float2*)(ws + OFF_TW);
  float2* TWR   = (float2*)(ws + OFF_TWR);
  int*    SORTN = (int*)(ws + OFF_SORTN);
  int*    TCNT  = (int*)(ws + OFF_TCNT);

  ln_stats_kernel<<<NB * LLEN, 256, 0, stream>>>(x, MEAN, RSTD);
  transpose_ln_kernel<<<dim3(LLEN / 32, DDIM / 32, NB), 256, 0, stream>>>(x, MEAN, RSTD, gamma, beta, UT);
  build_tables_kernel<<<67, 256, 0, stream>>>(Lr, Li, LAMR, LAMID, WRe, WIm, CUT, TWH, TWR);
  sortmodes_kernel<<<1, NMODE, 0, stream>>>(CUT, SORTN, TCNT);
  cpack_kernel<<<(NMODE * DDIM) / 256, 256, 0, stream>>>(Cr, Ci, WRe, WIm, SORTN, CPK);
  sbuild_kernel<<<dim3(SLEN / 256, NMODE), 256, 0, stream>>>(LAMR, LAMID, CUT, SORTN, SPK);
  kbuild7_kernel<<<dim3(DDIM / KB5_DT, NTILE), 256, 0, stream>>>(SPK, CPK, TCNT, KT);
  kf_fft_kernel<<<DDIM, 1024, 0, stream>>>(KT, TWH, TWR, KF);   // KF overwrites Spack (dead now)
  conv_fft_kernel<<<NB * DDIM, 1024, 0, stream>>>(UT, TWH, TWR, KF, pD);
  final_kernel<<<dim3(LLEN / 32, DDIM / 32, NB), 256, 0, stream>>>(UT, out);
}

// Round 20
// 291.936 us; speedup vs baseline: 1.2177x; 1.0243x over previous
//
#include <hip/hip_runtime.h>
#include <math.h>

#define LLEN 8192
#define DDIM 1024
#define NB   2
#define NMODE 512
#define MFFT 8192
#define SLEN 4096        // truncated kernel length (K[l]=0 beyond; worst-case e^-20)
#define KF_STRIDE 8208   // float2 per Kf row (8193 used)

// XOR-swizzled LDS index (bijective), buffer exactly 64 KB.
#define PIDX(i) ((i) ^ (((i) >> 4) & 15))
#define FBUF 8192        // float2 per buffer = 65,536 B exactly

// ---------------- workspace layout (bytes), total ~172.4 MB ----------------
#define OFF_UT   ((size_t)0)            // u_T [B,D,L] f32 (y+res in place)  67,108,864
#define OFF_KF   ((size_t)67108864)     // Kf [D,KF_STRIDE] float2           67,239,936
#define OFF_KT   ((size_t)134348800)    // K_T [D][SLEN] f32                 16,777,216
#define OFF_CPK  ((size_t)167903232)    // Cpk [512][1024] float2             4,194,304
#define OFF_MEAN ((size_t)172097536)    // mean [B,L] f32                        65,536
#define OFF_RSTD ((size_t)172163072)    // rstd [B,L] f32                        65,536
#define OFF_LAMR ((size_t)172228608)    // f32[512]
#define OFF_LAMID ((size_t)172230656)   // f64[512] (4096 B)
#define OFF_WR   ((size_t)172234752)    // f32[512]
#define OFF_WI   ((size_t)172236800)    // f32[512]
#define OFF_CUT  ((size_t)172238848)    // int[512]
#define OFF_TW   ((size_t)172240896)    // twH: 8192 float2 (hierarchical)      65,536
#define OFF_TWR  ((size_t)172306432)    // 8193 float2 (2pi k/16384)            65,544
#define OFF_SORTN ((size_t)172371976)   // int[512] rank->mode                    2,048
#define OFF_TCNT  ((size_t)172374024)   // int[16] per-l-tile active prefix          64
#define WS_NEED  ((size_t)172374088)

// Spack overlay inside the KF region (dead until kf_fft writes KF)
#define OFF_SP   OFF_KF

// ---------------- LayerNorm stats: mean/rstd per (b,l) row ----------------
__global__ __launch_bounds__(256) void ln_stats_kernel(const float* __restrict__ x,
                                                       float* __restrict__ mean,
                                                       float* __restrict__ rstd) {
  __shared__ float red[16];
  int row = blockIdx.x;            // b*L + l
  int tid = threadIdx.x;
  const float4* xr = (const float4*)(x + (size_t)row * DDIM);
  float4 v = xr[tid];
  float s = v.x + v.y + v.z + v.w;
  float q = v.x*v.x + v.y*v.y + v.z*v.z + v.w*v.w;
  #pragma unroll
  for (int off = 32; off; off >>= 1) { s += __shfl_down(s, off); q += __shfl_down(q, off); }
  int wid = tid >> 6;
  if ((tid & 63) == 0) { red[wid] = s; red[8 + wid] = q; }
  __syncthreads();
  if (tid == 0) {
    float ts = red[0] + red[1] + red[2] + red[3];
    float tq = red[8] + red[9] + red[10] + red[11];
    float m = ts * (1.0f / DDIM);
    float var = tq * (1.0f / DDIM) - m * m;
    mean[row] = m;
    rstd[row] = rsqrtf(var + 1e-5f);
  }
}

// ---------------- fused LN + transpose: x[B,L,D] -> uT[B,D,L] ----------------
__global__ __launch_bounds__(256) void transpose_ln_kernel(const float* __restrict__ x,
                                                           const float* __restrict__ mean,
                                                           const float* __restrict__ rstd,
                                                           const float* __restrict__ gamma,
                                                           const float* __restrict__ beta,
                                                           float* __restrict__ uT) {
  __shared__ float tile[32][33];
  int lt = blockIdx.x * 32, dt = blockIdx.y * 32, b = blockIdx.z;
  int c = threadIdx.x & 31, r0 = threadIdx.x >> 5;
  float gv = gamma[dt + c], bv = beta[dt + c];
  #pragma unroll
  for (int i = 0; i < 4; i++) {
    int r = r0 + i * 8;   // l within tile
    float m = mean[(size_t)b * LLEN + lt + r];
    float rs = rstd[(size_t)b * LLEN + lt + r];
    float xv = x[((size_t)b * LLEN + lt + r) * DDIM + dt + c];
    tile[r][c] = (xv - m) * rs * gv + bv;
  }
  __syncthreads();
  #pragma unroll
  for (int i = 0; i < 4; i++) {
    int r = r0 + i * 8;   // d within tile
    uT[((size_t)b * DDIM + dt + r) * LLEN + lt + c] = tile[c][r];
  }
}

// ---------------- params + twiddle tables (all one-time, double precision) ----------------
__global__ void build_tables_kernel(const float* __restrict__ Lr, const float* __restrict__ Li,
                                    float* lamr, double* lamid, float* wre, float* wim, int* cut,
                                    float2* twH, float2* twR) {
  int gid = blockIdx.x * 256 + threadIdx.x;
  if (gid < NMODE) {
    double lr = (double)Lr[gid], li = (double)Li[gid];
    double ar = -exp(lr);      // Re(Lam)  (negative)
    double ai = exp(li);       // Im(Lam)
    lamr[gid] = (float)ar;
    lamid[gid] = ai;
    double em = exp(ar);
    double cs = cos(ai), sn = sin(ai);
    double er = em * cs - 1.0;     // exp(Lam) - 1
    double ei = em * sn;
    double den = ar * ar + ai * ai;
    wre[gid] = (float)((er * ar + ei * ai) / den);   // (exp(Lam)-1)/Lam
    wim[gid] = (float)((ei * ar - er * ai) / den);
    int co = (int)(40.0 / (-ar)) + 1;                // exp(ar*l) < e^-40 beyond
    cut[gid] = co > SLEN ? SLEN : co;                // clamp to truncated domain
  }
  int j = gid - NMODE;
  if (j >= 0 && j < 8192) {
    // hierarchical twiddle: twH[Ls + p] = (cos(pi*p/Ls), +sin(pi*p/Ls)).
    // Applied as (w.x, sign*w.y): sign=-1 (fwd) -> e^{-i a}, sign=+1 (inv) -> e^{+i a}.
    if (j == 0) {
      twH[0] = make_float2(1.f, 0.f);
    } else {
      int lev = 31 - __clz(j);
      int Ls = 1 << lev;
      int p = j - Ls;
      double a = 3.14159265358979323846264338 * (double)p / (double)Ls;
      twH[j] = make_float2((float)cos(a), (float)sin(a));
    }
  }
  int k = gid - (NMODE + 8192);
  if (k >= 0 && k <= 8192) {
    double a = 6.283185307179586476925287 * (double)k / 16384.0;
    twR[k] = make_float2((float)cos(a), (float)sin(a));
  }
}

// ---------------- sort modes by cut descending (rank), per-tile prefix counts ----------------
#define KB4_LT 256
#define NTILE (SLEN / KB4_LT)   // 16
__global__ __launch_bounds__(NMODE) void sortmodes_kernel(const int* __restrict__ cut,
                                                          int* __restrict__ sortn,
                                                          int* __restrict__ tcount) {
  __shared__ int sc[NMODE];
  int tid = threadIdx.x;
  sc[tid] = cut[tid];
  __syncthreads();
  int c = sc[tid];
  int rank = 0;
  for (int m = 0; m < NMODE; ++m) {
    int cm = sc[m];
    rank += (cm > c) || (cm == c && m < tid);
  }
  sortn[rank] = tid;
  if (tid < NTILE) {
    int l0 = tid * KB4_LT;
    int cnt = 0;
    for (int m = 0; m < NMODE; ++m) cnt += (sc[m] > l0);
    tcount[tid] = cnt;
  }
}

// ---------------- Cpk[r][d] = (Cr[d][n]+i Ci[d][n]) * W[n], n = sortn[r] ----------------
__global__ __launch_bounds__(256) void cpack_kernel(const float* __restrict__ Cr,
                                                    const float* __restrict__ Ci,
                                                    const float* __restrict__ wre,
                                                    const float* __restrict__ wim,
                                                    const int* __restrict__ sortn,
                                                    float2* __restrict__ Cpk) {
  int idx = blockIdx.x * 256 + threadIdx.x;   // r*D + d  (d fastest -> coalesced writes)
  int r = idx >> 10, d = idx & (DDIM - 1);
  int n = sortn[r];
  float cr = Cr[(size_t)d * NMODE + n], ci = Ci[(size_t)d * NMODE + n];
  float wr = wre[n], wi = wim[n];
  Cpk[idx] = make_float2(cr * wr - ci * wi, cr * wi + ci * wr);
}

// ---------------- Spack[r][l] = exp(Lam_{sortn[r]} l), zero beyond cut ----------------
__global__ __launch_bounds__(256) void sbuild_kernel(const float* __restrict__ lamr,
                                                     const double* __restrict__ lamid,
                                                     const int* __restrict__ cut,
                                                     const int* __restrict__ sortn,
                                                     float2* __restrict__ Spack) {
  int r = blockIdx.y;
  int n = sortn[r];
  int l = blockIdx.x * 256 + threadIdx.x;
  float sr = 0.f, si = 0.f;
  if (l < cut[n]) {
    float mag = expf(lamr[n] * (float)l);
    double ph = lamid[n] * (double)l;
    const double tp = 6.283185307179586476925287;
    const double itp = 1.0 / 6.283185307179586476925287;
    ph -= floor(ph * itp) * tp;
    float cs, sn; sincosf((float)ph, &sn, &cs);
    sr = mag * cs; si = mag * sn;
  }
  Spack[(size_t)r * SLEN + l] = make_float2(sr, si);
}

// ---------------- KT[d,l] = sum_{r<nact} (Sr*Cr - Si*Ci), 8-deep prefetch ----------
// Grid: (DDIM/KB5_DT, NTILE) — d-group is the FAST blockIdx dim so the heavy
// t=0 blocks (ids 0..255) round-robin across all 8 XCDs. (Round-10 lesson.)
#define KB5_DT 4
__global__ __launch_bounds__(256) void kbuild7_kernel(const float2* __restrict__ Spack,
                                                      const float2* __restrict__ Cpk,
                                                      const int* __restrict__ tcount,
                                                      float* __restrict__ KT) {
  __shared__ float2 sC[NMODE][KB5_DT];
  int t = blockIdx.y;
  int d0 = blockIdx.x * KB5_DT;
  int tid = threadIdx.x;
  int nact = tcount[t];
  for (int i = tid; i < nact * KB5_DT; i += 256) {
    int r = i >> 2, dd = i & 3;
    sC[r][dd] = Cpk[(size_t)r * DDIM + d0 + dd];
  }
  __syncthreads();
  int l = t * KB4_LT + tid;
  float acc0 = 0.f, acc1 = 0.f, acc2 = 0.f, acc3 = 0.f;
  const float2* sp = Spack + l;
  int i = 0;
  int n8 = nact & ~7;
  for (; i < n8; i += 8) {
    const float2* p = sp + (size_t)i * SLEN;
    float2 s0 = p[0];
    float2 s1 = p[(size_t)1 * SLEN];
    float2 s2 = p[(size_t)2 * SLEN];
    float2 s3 = p[(size_t)3 * SLEN];
    float2 s4 = p[(size_t)4 * SLEN];
    float2 s5 = p[(size_t)5 * SLEN];
    float2 s6 = p[(size_t)6 * SLEN];
    float2 s7 = p[(size_t)7 * SLEN];
    #define KACC(ss, rr) { \
      float2 c0 = sC[rr][0], c1 = sC[rr][1], c2 = sC[rr][2], c3 = sC[rr][3]; \
      acc0 += ss.x * c0.x - ss.y * c0.y; \
      acc1 += ss.x * c1.x - ss.y * c1.y; \
      acc2 += ss.x * c2.x - ss.y * c2.y; \
      acc3 += ss.x * c3.x - ss.y * c3.y; }
    KACC(s0, i + 0) KACC(s1, i + 1) KACC(s2, i + 2) KACC(s3, i + 3)
    KACC(s4, i + 4) KACC(s5, i + 5) KACC(s6, i + 6) KACC(s7, i + 7)
  }
  for (; i < nact; ++i) {
    float2 s0 = sp[(size_t)i * SLEN];
    KACC(s0, i)
  }
  #undef KACC
  KT[(size_t)(d0 + 0) * SLEN + l] = acc0;
  KT[(size_t)(d0 + 1) * SLEN + l] = acc1;
  KT[(size_t)(d0 + 2) * SLEN + l] = acc2;
  KT[(size_t)(d0 + 3) * SLEN + l] = acc3;
}

// ================= radix-8 building blocks (verified algebra, rounds 11-16) =================
// R4BLK: verified radix-4 block. Inputs b0,b2,b1,b3; twiddles wa, wb; outputs o0..o3.
#define R4BLK(b0, b2, b1, b3, wa, wb, o0, o1, o2, o3) { \
  float war=(wa).x, wai=sign*(wa).y, wbr=(wb).x, wbi=sign*(wb).y; \
  float t1r_=war*(b2).x - wai*(b2).y, t1i_=war*(b2).y + wai*(b2).x; \
  float t3r_=war*(b3).x - wai*(b3).y, t3i_=war*(b3).y + wai*(b3).x; \
  float Ar=(b0).x+t1r_, Ai=(b0).y+t1i_, Cr=(b0).x-t1r_, Ci=(b0).y-t1i_; \
  float Br=(b1).x+t3r_, Bi=(b1).y+t3i_, Dr=(b1).x-t3r_, Di=(b1).y-t3i_; \
  float Er=wbr*Br-wbi*Bi, Ei=wbr*Bi+wbi*Br; \
  float Fr=wbr*Dr-wbi*Di, Fi=wbr*Di+wbi*Dr; \
  dst[PIDX(o0)]=make_float2(Ar+Er,Ai+Ei); \
  dst[PIDX(o1)]=make_float2(Cr-sign*Fi,Ci+sign*Fr); \
  dst[PIDX(o2)]=make_float2(Ar-Er,Ai-Ei); \
  dst[PIDX(o3)]=make_float2(Cr+sign*Fi,Ci-sign*Fr); }

// stage-0 twiddle constants: twH[1]=twH[2]=twH[4]=(1,0), twH[3]=(0,1), twH[5]=(r2,r2)
#define TW_1 make_float2(1.f, 0.f)
#define TW_I make_float2(0.f, 1.f)
#define TW_Q make_float2(0.70710678118654752f, 0.70710678118654752f)

// IN-PLACE radix-8 stage: read 8 + level-1 into regs, barrier, write 8.
// Caller must __syncthreads() after.
__device__ __forceinline__ void r8_stage_ip(float2* buf, const float2* __restrict__ twH,
                                            int tid, float sign, int s) {
  int L = 1 << s;
  int j = tid;
  int p = j & (L - 1);
  int q = j >> s;
  float2 x0 = buf[PIDX(j)];
  float2 x1 = buf[PIDX(j + 1024)];
  float2 x2 = buf[PIDX(j + 2048)];
  float2 x3 = buf[PIDX(j + 3072)];
  float2 x4 = buf[PIDX(j + 4096)];
  float2 x5 = buf[PIDX(j + 5120)];
  float2 x6 = buf[PIDX(j + 6144)];
  float2 x7 = buf[PIDX(j + 7168)];
  float2 w1 = twH[L + p];
  float w1r = w1.x, w1i = sign * w1.y;
  float t4r = w1r*x4.x - w1i*x4.y, t4i = w1r*x4.y + w1i*x4.x;
  float t5r = w1r*x5.x - w1i*x5.y, t5i = w1r*x5.y + w1i*x5.x;
  float t6r = w1r*x6.x - w1i*x6.y, t6i = w1r*x6.y + w1i*x6.x;
  float t7r = w1r*x7.x - w1i*x7.y, t7i = w1r*x7.y + w1i*x7.x;
  float2 A0 = make_float2(x0.x + t4r, x0.y + t4i), B0 = make_float2(x0.x - t4r, x0.y - t4i);
  float2 A1 = make_float2(x1.x + t5r, x1.y + t5i), B1 = make_float2(x1.x - t5r, x1.y - t5i);
  float2 A2 = make_float2(x2.x + t6r, x2.y + t6i), B2 = make_float2(x2.x - t6r, x2.y - t6i);
  float2 A3 = make_float2(x3.x + t7r, x3.y + t7i), B3 = make_float2(x3.x - t7r, x3.y - t7i);
  __syncthreads();           // all reads complete before any writes
  float2* dst = buf;
  int O = (q << (s + 3)) + p;
  R4BLK(A0, A2, A1, A3, twH[2*L + p], twH[4*L + p], O, O + 2*L, O + 4*L, O + 6*L)
  R4BLK(B0, B2, B1, B3, twH[3*L + p], twH[5*L + p], O + L, O + 3*L, O + 5*L, O + 7*L)
}

// fused forward-final-radix-2: Z[k] and Z[8192-k] from pre-final state s[] (1<=k<=4095).
__device__ __forceinline__ void fwd_final_pair(const float2* sbuf, const float2* __restrict__ twH,
                                               int k, float2* zk, float2* zm) {
  float2 a1 = sbuf[PIDX(k)], b1 = sbuf[PIDX(k + 4096)];
  float2 w1 = twH[4096 + k];
  float br1 = w1.x*b1.x + w1.y*b1.y;   // sign=-1: w_eff = (w.x, -w.y)
  float bi1 = w1.x*b1.y - w1.y*b1.x;
  *zk = make_float2(a1.x + br1, a1.y + bi1);
  float2 a2 = sbuf[PIDX(4096 - k)], b2 = sbuf[PIDX(8192 - k)];
  float2 w2 = twH[8192 - k];
  float br2 = w2.x*b2.x + w2.y*b2.y;
  float bi2 = w2.x*b2.y - w2.y*b2.x;
  *zm = make_float2(a2.x - br2, a2.y - bi2);
}

// Hermitian split + spectral multiply + inverse-repack for conjugate pair (k, 8192-k)
__device__ __forceinline__ void pw_pair(float2 zk, float2 zm, int k,
                                        const float2* __restrict__ twR,
                                        const float2* __restrict__ kf,
                                        float2* outk, float2* outm) {
  float Ar = 0.5f * (zk.x + zm.x), Ai = 0.5f * (zk.y - zm.y);
  float Br = 0.5f * (zk.x - zm.x), Bi = 0.5f * (zk.y + zm.y);
  float2 t = twR[k];
  float c = t.x, sn = t.y;
  float e1r = sn * Br - c * Bi;
  float e1i = sn * Bi + c * Br;
  float Ukr = Ar - e1r, Uki = Ai - e1i;      // U[k]
  float Umr = Ar + e1r, Umi = -Ai - e1i;     // U[8192-k]
  float2 kk = kf[k], km = kf[MFFT - k];
  float Ykr = Ukr * kk.x - Uki * kk.y, Yki = Ukr * kk.y + Uki * kk.x;
  float Ymr = Umr * km.x - Umi * km.y, Ymi = Umr * km.y + Umi * km.x;
  float Eyr = 0.5f * (Ykr + Ymr), Eyi = 0.5f * (Yki - Ymi);
  float Byr = 0.5f * (Ykr - Ymr), Byi = 0.5f * (Yki + Ymi);
  *outk = make_float2(Eyr - sn * Byr - c * Byi, Eyi + c * Byr - sn * Byi);
  *outm = make_float2(Eyr + sn * Byr + c * Byi, -Eyi + c * Byr - sn * Byi);
}

__device__ __forceinline__ void pw_compute(const float2* buf, const float2* __restrict__ twH,
                                           const float2* __restrict__ twR,
                                           const float2* __restrict__ kf,
                                           int k, float2* outk, float2* outm) {
  float2 zk, zm;
  fwd_final_pair(buf, twH, k, &zk, &zm);
  pw_pair(zk, zm, k, twR, kf, outk, outm);
}

// ---------------- Kf[d,k] = rfft16384(K_T[d]) / 8192, k=0..8192 ----------------
__global__ __launch_bounds__(1024, 4) void kf_fft_kernel(const float* __restrict__ KT,
                                                         const float2* __restrict__ twH,
                                                         const float2* __restrict__ twR,
                                                         float2* __restrict__ Kf) {
  __shared__ float2 buf[FBUF];
  int d = blockIdx.x;
  int tid = threadIdx.x;
  const float2* row = (const float2*)(KT + (size_t)d * SLEN);   // 2048 float2
  const float sign = -1.f;
  {   // first radix-8 stage fused with global load (inputs 2048.. are zero)
    float2* dst = buf;
    float2 x0 = row[tid];
    float2 x1 = row[tid + 1024];
    float2 zf = make_float2(0.f, 0.f);
    int O = tid << 3;
    R4BLK(x0, zf, x1, zf, TW_1, TW_1, O, O + 2, O + 4, O + 6)
    R4BLK(x0, zf, x1, zf, TW_I, TW_Q, O + 1, O + 3, O + 5, O + 7)
  }
  __syncthreads();
  r8_stage_ip(buf, twH, tid, sign, 3);
  __syncthreads();
  r8_stage_ip(buf, twH, tid, sign, 6);
  __syncthreads();
  r8_stage_ip(buf, twH, tid, sign, 9);
  __syncthreads();
  // fused final radix-2 + Hermitian split + scale -> global (read-only on buf)
  const float scale = 1.0f / 8192.0f;         // fold inverse-FFT 1/8192 here
  float2* out = Kf + (size_t)d * KF_STRIDE;
  for (int k = tid; k <= 4096; k += 1024) {
    if (k == 0) {
      float2 s0 = buf[PIDX(0)], s4 = buf[PIDX(4096)];
      float2 z0 = make_float2(s0.x + s4.x, s0.y + s4.y);
      out[0]    = make_float2((z0.x + z0.y) * scale, 0.f);
      out[8192] = make_float2((z0.x - z0.y) * scale, 0.f);
    } else {
      float2 zk, zm;
      if (k == 4096) {
        float2 s0 = buf[PIDX(0)], s4 = buf[PIDX(4096)];
        zk = make_float2(s0.x - s4.x, s0.y - s4.y);
        zm = zk;
      } else {
        fwd_final_pair(buf, twH, k, &zk, &zm);
      }
      float Ar = 0.5f * (zk.x + zm.x), Ai = 0.5f * (zk.y - zm.y);
      float Br = 0.5f * (zk.x - zm.x), Bi = 0.5f * (zk.y + zm.y);
      float2 t = twR[k];
      float c = t.x, sn = t.y;
      float e1r = sn * Br - c * Bi;
      float e1i = sn * Bi + c * Br;
      out[k]        = make_float2((Ar - e1r) * scale, (Ai - e1i) * scale);
      out[MFFT - k] = make_float2((Ar + e1r) * scale, (-Ai - e1i) * scale);
    }
  }
}

// ---------------- conv: y = irfft(rfft(u) * Kf) + u*pD, in-place over uT row ----------------
// Single 64KB swizzled LDS buffer, all stages in place (round-16 best config).
// Pointwise runs as two closed phases (read-set == write-set, verified):
//   A: {k, 4096-k} for k in [1,1024) plus {0, 4096}
//   B: {1024+t, 3072-t} for t in [0,1024) plus {2048}
__global__ __launch_bounds__(1024, 4) void conv_fft_kernel(float* __restrict__ uT,
                                                           const float2* __restrict__ twH,
                                                           const float2* __restrict__ twR,
                                                           const float2* __restrict__ Kf,
                                                           const float* __restrict__ pD) {
  __shared__ float2 buf[FBUF];
  int wg = blockIdx.x;
  int b = wg >> 10, d = wg & (DDIM - 1);
  int tid = threadIdx.x;
  float2* row = (float2*)(uT + ((size_t)b * DDIM + d) * LLEN);  // 4096 float2 of u
  float sign = -1.f;
  const float2* kf = Kf + (size_t)d * KF_STRIDE;
  {   // first radix-8 stage fused with global load (inputs 4096.. are zero)
    float2* dst = buf;
    float2 x0 = row[tid];
    float2 x1 = row[tid + 1024];
    float2 x2 = row[tid + 2048];
    float2 x3 = row[tid + 3072];
    int O = tid << 3;   // x4..x7 = 0 -> A_m = B_m = x_m
    R4BLK(x0, x2, x1, x3, TW_1, TW_1, O, O + 2, O + 4, O + 6)
    R4BLK(x0, x2, x1, x3, TW_I, TW_Q, O + 1, O + 3, O + 5, O + 7)
  }
  __syncthreads();
  r8_stage_ip(buf, twH, tid, sign, 3);
  __syncthreads();
  r8_stage_ip(buf, twH, tid, sign, 6);
  __syncthreads();
  r8_stage_ip(buf, twH, tid, sign, 9);
  __syncthreads();
  // ---- pointwise phase A ----
  {
    float2 oA0, oA1, oB0, oB1;
    if (tid == 0) {
      float2 s0 = buf[PIDX(0)], s4 = buf[PIDX(4096)];
      float2 z0 = make_float2(s0.x + s4.x, s0.y + s4.y);
      float U0 = z0.x + z0.y;
      float UM = z0.x - z0.y;
      float Y0 = U0 * kf[0].x;
      float YM = UM * kf[8192].x;
      oA0 = make_float2(0.5f * (Y0 + YM), 0.5f * (Y0 - YM));
      float2 zk = make_float2(s0.x - s4.x, s0.y - s4.y);   // k=4096 (self-conjugate)
      float2 dum;
      pw_pair(zk, zk, 4096, twR, kf, &oB0, &dum);
      oA1 = oB1 = make_float2(0.f, 0.f);
    } else {
      pw_compute(buf, twH, twR, kf, tid, &oA0, &oA1);
      pw_compute(buf, twH, twR, kf, 4096 - tid, &oB0, &oB1);
    }
    __syncthreads();
    if (tid == 0) {
      buf[PIDX(0)] = oA0;
      buf[PIDX(4096)] = oB0;
    } else {
      buf[PIDX(tid)] = oA0;        buf[PIDX(8192 - tid)] = oA1;
      buf[PIDX(4096 - tid)] = oB0; buf[PIDX(4096 + tid)] = oB1;
    }
    __syncthreads();
  }
  // ---- pointwise phase B ----
  {
    float2 oC0, oC1, oD0, oD1, oE0, oE1;
    int kC = 1024 + tid;    // [1024, 2048)
    int kD = 3072 - tid;    // (2048, 3072]
    pw_compute(buf, twH, twR, kf, kC, &oC0, &oC1);
    pw_compute(buf, twH, twR, kf, kD, &oD0, &oD1);
    if (tid == 0) pw_compute(buf, twH, twR, kf, 2048, &oE0, &oE1);
    __syncthreads();
    buf[PIDX(kC)] = oC0; buf[PIDX(8192 - kC)] = oC1;
    buf[PIDX(kD)] = oD0; buf[PIDX(8192 - kD)] = oD1;
    if (tid == 0) { buf[PIDX(2048)] = oE0; buf[PIDX(6144)] = oE1; }
    __syncthreads();
  }
  // ---- inverse FFT: 4 in-place radix-8 stages + fused final radix-2 in epilogue ----
  sign = +1.f;
  r8_stage_ip(buf, twH, tid, sign, 0);
  __syncthreads();
  r8_stage_ip(buf, twH, tid, sign, 3);
  __syncthreads();
  r8_stage_ip(buf, twH, tid, sign, 6);
  __syncthreads();
  r8_stage_ip(buf, twH, tid, sign, 9);
  __syncthreads();
  // fused inverse final radix-2 (only lower half needed) + residual -> global
  float pdv = pD[d];
  for (int j = tid; j < 4096; j += 1024) {
    float2 a = buf[PIDX(j)];
    float2 bq = buf[PIDX(j + 4096)];
    float2 w = twH[4096 + j];           // inv: wi = +w.y
    float br = w.x * bq.x - w.y * bq.y;
    float bi = w.x * bq.y + w.y * bq.x;
    float2 uv = row[j];                 // original u (untouched so far)
    row[j] = make_float2(a.x + br + uv.x * pdv, a.y + bi + uv.y * pdv);
  }
}

// ---------------- out[b,l,d] = yT[b,d,l] (transpose back) ----------------
__global__ __launch_bounds__(256) void final_kernel(const float* __restrict__ yT,
                                                    float* __restrict__ out) {
  __shared__ float tile[32][33];
  int lt = blockIdx.x * 32, dt = blockIdx.y * 32, b = blockIdx.z;
  int c = threadIdx.x & 31, r0 = threadIdx.x >> 5;
  #pragma unroll
  for (int i = 0; i < 4; i++) {
    int r = r0 + i * 8;   // d within tile
    tile[r][c] = yT[((size_t)b * DDIM + dt + r) * LLEN + lt + c];
  }
  __syncthreads();
  #pragma unroll
  for (int i = 0; i < 4; i++) {
    int r = r0 + i * 8;   // l within tile
    out[((size_t)b * LLEN + lt + r) * DDIM + dt + c] = tile[c][r];
  }
}

extern "C" void kernel_launch(void* const* d_in, const int* in_sizes, int n_in,
                              void* d_out, int out_size, void* d_ws, size_t ws_size,
                              hipStream_t stream) {
  (void)in_sizes; (void)n_in; (void)out_size;
  if (ws_size < WS_NEED) return;   // safety: fail cleanly (wrong output) instead of faulting
  const float* x     = (const float*)d_in[0];
  const float* Lr    = (const float*)d_in[1];
  const float* Li    = (const float*)d_in[2];
  const float* Cr    = (const float*)d_in[3];
  const float* Ci    = (const float*)d_in[4];
  const float* pD    = (const float*)d_in[5];
  const float* gamma = (const float*)d_in[6];
  const float* beta  = (const float*)d_in[7];
  float* out = (float*)d_out;
  char* ws = (char*)d_ws;

  float*  UT    = (float*)(ws + OFF_UT);
  float2* KF    = (float2*)(ws + OFF_KF);
  float2* SPK   = (float2*)(ws + OFF_SP);   // overlaid on KF region
  float*  KT    = (float*)(ws + OFF_KT);
  float2* CPK   = (float2*)(ws + OFF_CPK);
  float*  MEAN  = (float*)(ws + OFF_MEAN);
  float*  RSTD  = (float*)(ws + OFF_RSTD);
  float*  LAMR  = (float*)(ws + OFF_LAMR);
  double* LAMID = (double*)(ws + OFF_LAMID);
  float*  WRe   = (float*)(ws + OFF_WR);
  float*  WIm   = (float*)(ws + OFF_WI);
  int*    CUT   = (int*)(ws + OFF_CUT);
  float2* TWH   = (float2*)(ws + OFF_TW);
  float2* TWR   = (float2*)(ws + OFF_TWR);
  int*    SORTN = (int*)(ws + OFF_SORTN);
  int*    TCNT  = (int*)(ws + OFF_TCNT);

  ln_stats_kernel<<<NB * LLEN, 256, 0, stream>>>(x, MEAN, RSTD);
  transpose_ln_kernel<<<dim3(LLEN / 32, DDIM / 32, NB), 256, 0, stream>>>(x, MEAN, RSTD, gamma, beta, UT);
  build_tables_kernel<<<67, 256, 0, stream>>>(Lr, Li, LAMR, LAMID, WRe, WIm, CUT, TWH, TWR);
  sortmodes_kernel<<<1, NMODE, 0, stream>>>(CUT, SORTN, TCNT);
  cpack_kernel<<<(NMODE * DDIM) / 256, 256, 0, stream>>>(Cr, Ci, WRe, WIm, SORTN, CPK);
  sbuild_kernel<<<dim3(SLEN / 256, NMODE), 256, 0, stream>>>(LAMR, LAMID, CUT, SORTN, SPK);
  kbuild7_kernel<<<dim3(DDIM / KB5_DT, NTILE), 256, 0, stream>>>(SPK, CPK, TCNT, KT);
  kf_fft_kernel<<<DDIM, 1024, 0, stream>>>(KT, TWH, TWR, KF);   // KF overwrites Spack (dead now)
  conv_fft_kernel<<<NB * DDIM, 1024, 0, stream>>>(UT, TWH, TWR, KF, pD);
  final_kernel<<<dim3(LLEN / 32, DDIM / 32, NB), 256, 0, stream>>>(UT, out);
}